// Round 1
// baseline (72.540 us; speedup 1.0000x reference)
//
#include <hip/hip_runtime.h>
#include <math.h>

// Problem constants (from reference): feedback (32,16,512) fp32, embed (1024,4) fp32
// rows = 32*16 = 512, D = 512, VQ_DIM = 4, g = 128 groups/row, K = 1024 codes.
#define ROWS 512
#define DIMS 512
#define KCODES 1024
#define NGRP 128           // groups per row
#define NT 256             // threads per block
// Per thread: G=8 groups held in registers, coverage C=16 threads/group, 64 codes/thread.

__global__ __launch_bounds__(NT) void vq_main(const float* __restrict__ feedback,
                                              const float* __restrict__ embed,
                                              float* __restrict__ out,
                                              float* __restrict__ partial)
{
    __shared__ float4 s_code[KCODES];   // (-2*e0, -2*e1, -2*e2, -2*e3)
    __shared__ float  s_ee[KCODES];     // ||e||^2
    __shared__ float  s_f[DIMS];        // raw feedback row
    __shared__ float  s_dp[NGRP * 16];  // merge: partial dmin
    __shared__ int    s_ip[NGRP * 16];  // merge: partial argmin
    __shared__ float  s_red[4];

    const int row = blockIdx.x;
    const int tid = threadIdx.x;
    const float* frow = feedback + row * DIMS;

    // ---- stage codebook into LDS (coalesced float4 loads) ----
    #pragma unroll
    for (int r = 0; r < 4; ++r) {
        int k = tid + r * NT;
        float4 e = ((const float4*)embed)[k];
        s_code[k] = make_float4(-2.f * e.x, -2.f * e.y, -2.f * e.z, -2.f * e.w);
        s_ee[k] = e.x * e.x + e.y * e.y + e.z * e.z + e.w * e.w;
    }

    // ---- stage row + row norm ----
    float2 f2 = ((const float2*)frow)[tid];
    ((float2*)s_f)[tid] = f2;
    float ss = f2.x * f2.x + f2.y * f2.y;
    #pragma unroll
    for (int off = 32; off > 0; off >>= 1) ss += __shfl_down(ss, off, 64);
    if ((tid & 63) == 0) s_red[tid >> 6] = ss;
    __syncthreads();
    const float sumsq = s_red[0] + s_red[1] + s_red[2] + s_red[3];
    const float scale = sqrtf(sumsq);
    const float inv   = 1.0f / scale;

    // ---- FloatBiter(scale): faithful, log2 path gives exactly 2.0 at the clip ----
    float xc = fminf(fmaxf(scale + 1.0f, 1.0f), 16.0f);
    float lg = log2f(xc) * 0.5f;     // == log(xc)/log(4); exact 2.0 at xc=16
    float sbits = 0.f, base = 1.f;
    #pragma unroll
    for (int i = 0; i < 8; ++i) {
        int b = ((int)floorf(lg * base)) & 1;   // bits >= 0 so %2 == &1
        sbits += (float)b / base;
        base *= 2.f;
    }
    const float scale_q = exp2f(2.0f * sbits) - 1.0f;   // 4^s - 1

    // ---- per-thread group fragments: groups [8j, 8j+8), codes [64c, 64c+64) ----
    const int j = tid & 15;    // group block
    const int c = tid >> 4;    // code-range coverage index
    float fn[32];
    #pragma unroll
    for (int i = 0; i < 8; ++i) {
        float4 v = ((float4*)s_f)[j * 8 + i];
        fn[4 * i + 0] = v.x * inv; fn[4 * i + 1] = v.y * inv;
        fn[4 * i + 2] = v.z * inv; fn[4 * i + 3] = v.w * inv;
    }
    float dmin[8]; int kmin[8];
    #pragma unroll
    for (int jj = 0; jj < 8; ++jj) { dmin[jj] = 1e30f; kmin[jj] = 0; }

    const int kbeg = c * 64;
    for (int k = kbeg; k < kbeg + 64; ++k) {
        float4 cc = s_code[k];
        float  ee = s_ee[k];
        #pragma unroll
        for (int jj = 0; jj < 8; ++jj) {
            // d = ||e||^2 - 2*dot(fn, e)  (xx omitted: constant per group, preserves argmin)
            float d = fmaf(cc.x, fn[4 * jj + 0],
                      fmaf(cc.y, fn[4 * jj + 1],
                      fmaf(cc.z, fn[4 * jj + 2],
                      fmaf(cc.w, fn[4 * jj + 3], ee))));
            if (d < dmin[jj]) { dmin[jj] = d; kmin[jj] = k; }
        }
    }

    // ---- write partial minima for merge ----
    #pragma unroll
    for (int jj = 0; jj < 8; ++jj) {
        int g = j * 8 + jj;
        s_dp[g * 16 + c] = dmin[jj];
        s_ip[g * 16 + c] = kmin[jj];
    }
    __syncthreads();

    // ---- merge (ascending k => first-occurrence tie-break), epilogue ----
    float lsum = 0.f;
    if (tid < NGRP) {
        const int g = tid;
        float dm = s_dp[g * 16 + 0];
        int   km = s_ip[g * 16 + 0];
        #pragma unroll
        for (int cc2 = 1; cc2 < 16; ++cc2) {
            float dv = s_dp[g * 16 + cc2];
            int   kv = s_ip[g * 16 + cc2];
            if (dv < dm) { dm = dv; km = kv; }
        }
        float4 code = s_code[km];
        float e0 = -0.5f * code.x, e1 = -0.5f * code.y,
              e2 = -0.5f * code.z, e3 = -0.5f * code.w;
        float4 fv = ((float4*)s_f)[g];
        float x0 = fv.x * inv, x1 = fv.y * inv, x2 = fv.z * inv, x3 = fv.w * inv;
        // loss computed directly as sum (fqn - fn)^2 — faithful to reference
        float d0 = e0 - x0, d1 = e1 - x1, d2 = e2 - x2, d3 = e3 - x3;
        lsum = d0 * d0 + d1 * d1 + d2 * d2 + d3 * d3;
        // out = fqn * scale_q (straight-through forward value)
        ((float4*)out)[row * NGRP + g] =
            make_float4(e0 * scale_q, e1 * scale_q, e2 * scale_q, e3 * scale_q);
    }
    #pragma unroll
    for (int off = 32; off > 0; off >>= 1) lsum += __shfl_down(lsum, off, 64);
    __syncthreads();                     // s_red reuse is safe: all prior reads done
    if ((tid & 63) == 0 && tid < NGRP) s_red[tid >> 6] = lsum;  // waves 0,1 only
    __syncthreads();
    if (tid == 0) partial[row] = s_red[0] + s_red[1];
}

__global__ __launch_bounds__(256) void vq_finish(const float* __restrict__ partial,
                                                 float* __restrict__ out_loss)
{
    __shared__ float r[4];
    float v = partial[threadIdx.x] + partial[threadIdx.x + 256];
    #pragma unroll
    for (int off = 32; off > 0; off >>= 1) v += __shfl_down(v, off, 64);
    if ((threadIdx.x & 63) == 0) r[threadIdx.x >> 6] = v;
    __syncthreads();
    if (threadIdx.x == 0) {
        float t = (r[0] + r[1] + r[2] + r[3]) / 262144.f;  // mean over b*p*g*VQ_DIM
        out_loss[0] = t;   // loss1
        out_loss[1] = t;   // loss2 (same forward value)
    }
}

extern "C" void kernel_launch(void* const* d_in, const int* in_sizes, int n_in,
                              void* d_out, int out_size, void* d_ws, size_t ws_size,
                              hipStream_t stream) {
    const float* feedback = (const float*)d_in[0];   // 262144 fp32
    const float* embed    = (const float*)d_in[1];   // 4096 fp32
    float* out     = (float*)d_out;                  // [262144 out | loss1 | loss2]
    float* partial = (float*)d_ws;                   // 512 fp32 row partials

    vq_main<<<ROWS, NT, 0, stream>>>(feedback, embed, out, partial);
    vq_finish<<<1, 256, 0, stream>>>(partial, out + ROWS * DIMS);
}

// Round 2
// 69.590 us; speedup vs baseline: 1.0424x; 1.0424x over previous
//
#include <hip/hip_runtime.h>
#include <math.h>

// feedback (32,16,512) fp32, embed (1024,4) fp32
// rows=512, D=512, VQ_DIM=4, g=128 groups/row, K=1024 codes.
#define ROWS 512
#define DIMS 512
#define KCODES 1024
#define NGRP 128
#define NT 256
// Per thread: 8 groups (as 4 packed pairs), 64 codes; coverage 16 threads/group.

typedef float v2f __attribute__((ext_vector_type(2)));

__global__ __launch_bounds__(NT) void vq_main(const float* __restrict__ feedback,
                                              const float* __restrict__ embed,
                                              float* __restrict__ out,
                                              float* __restrict__ partial)
{
    // +16 padding: one extra slot per 64-code block so the 4 per-wave coverage
    // addresses (stride 64 codes) land on distinct banks (conflict-free).
    __shared__ float4 s_code[KCODES + 16];   // (-2e0,-2e1,-2e2,-2e3)
    __shared__ float  s_ee[KCODES + 16];     // ||e||^2 + 4  (keeps d>0: 2xe<=xx+ee, xx<=1)
    __shared__ float  s_f[DIMS];
    __shared__ int    s_kp[NGRP * 16];       // packed (dist|k) partial minima
    __shared__ float  s_red[4];

    const int row = blockIdx.x;
    const int tid = threadIdx.x;

    // ---- stage codebook (coalesced float4) ----
    #pragma unroll
    for (int r = 0; r < 4; ++r) {
        int k = tid + r * NT;
        int kp = k + (k >> 6);
        float4 e = ((const float4*)embed)[k];
        s_code[kp] = make_float4(-2.f * e.x, -2.f * e.y, -2.f * e.z, -2.f * e.w);
        s_ee[kp] = e.x * e.x + e.y * e.y + e.z * e.z + e.w * e.w + 4.0f;
    }

    // ---- stage row + row norm ----
    float2 f2 = ((const float2*)(feedback + row * DIMS))[tid];
    ((float2*)s_f)[tid] = f2;
    float ss = f2.x * f2.x + f2.y * f2.y;
    #pragma unroll
    for (int off = 32; off > 0; off >>= 1) ss += __shfl_down(ss, off, 64);
    if ((tid & 63) == 0) s_red[tid >> 6] = ss;
    __syncthreads();
    const float sumsq = s_red[0] + s_red[1] + s_red[2] + s_red[3];
    const float scale = sqrtf(sumsq);
    const float inv   = 1.0f / scale;

    // ---- FloatBiter(scale): log2 path gives exactly 2.0 at the 16.0 clip ----
    float xc = fminf(fmaxf(scale + 1.0f, 1.0f), 16.0f);
    float lg = log2f(xc) * 0.5f;
    float sbits = 0.f, base = 1.f;
    #pragma unroll
    for (int i = 0; i < 8; ++i) {
        int b = ((int)floorf(lg * base)) & 1;
        sbits += (float)b / base;
        base *= 2.f;
    }
    const float scale_q = exp2f(2.0f * sbits) - 1.0f;

    // ---- per-thread fragments: groups [8j,8j+8) as 4 pairs, codes [64c,64c+64) ----
    const int j = tid & 15;
    const int c = tid >> 4;
    v2f fnp[4][4];                       // [pair][dim] = (fn[2p][d], fn[2p+1][d])
    #pragma unroll
    for (int p = 0; p < 4; ++p) {
        float4 a = ((float4*)s_f)[j * 8 + 2 * p];
        float4 b = ((float4*)s_f)[j * 8 + 2 * p + 1];
        fnp[p][0] = (v2f){a.x * inv, b.x * inv};
        fnp[p][1] = (v2f){a.y * inv, b.y * inv};
        fnp[p][2] = (v2f){a.z * inv, b.z * inv};
        fnp[p][3] = (v2f){a.w * inv, b.w * inv};
    }
    int keymin[8];
    #pragma unroll
    for (int i = 0; i < 8; ++i) keymin[i] = 0x7FFFFFFF;

    const float4* codeP = s_code + c * 65;   // padded base of this c-block
    const float*  eeP   = s_ee   + c * 65;
    const int kbase = c * 64;
    #pragma unroll 4
    for (int i = 0; i < 64; ++i) {
        float4 cc = codeP[i];
        float  eb = eeP[i];
        int kk = kbase + i;
        #pragma unroll
        for (int p = 0; p < 4; ++p) {
            v2f acc = (v2f){eb, eb};
            acc = __builtin_elementwise_fma((v2f){cc.x, cc.x}, fnp[p][0], acc);
            acc = __builtin_elementwise_fma((v2f){cc.y, cc.y}, fnp[p][1], acc);
            acc = __builtin_elementwise_fma((v2f){cc.z, cc.z}, fnp[p][2], acc);
            acc = __builtin_elementwise_fma((v2f){cc.w, cc.w}, fnp[p][3], acc);
            // d>0 always => positive-float bits order as ints; low 10 bits -> k
            // (truncation flips only sub-1e-3 near-ties: invisible at 2% loss tol)
            int k0 = (__float_as_int(acc.x) & 0xFFFFFC00) | kk;
            int k1 = (__float_as_int(acc.y) & 0xFFFFFC00) | kk;
            keymin[2 * p]     = min(keymin[2 * p],     k0);
            keymin[2 * p + 1] = min(keymin[2 * p + 1], k1);
        }
    }
    #pragma unroll
    for (int p = 0; p < 8; ++p) s_kp[(j * 8 + p) * 16 + c] = keymin[p];
    __syncthreads();

    // ---- merge (int-min == dist-min, smaller k on tie), epilogue ----
    float lsum = 0.f;
    if (tid < NGRP) {
        int key = s_kp[tid * 16];
        #pragma unroll
        for (int c2 = 1; c2 < 16; ++c2) key = min(key, s_kp[tid * 16 + c2]);
        int km = key & 1023;
        float4 code = s_code[km + (km >> 6)];
        float e0 = -0.5f * code.x, e1 = -0.5f * code.y,
              e2 = -0.5f * code.z, e3 = -0.5f * code.w;
        float4 fv = ((float4*)s_f)[tid];
        float x0 = fv.x * inv, x1 = fv.y * inv, x2 = fv.z * inv, x3 = fv.w * inv;
        float d0 = e0 - x0, d1 = e1 - x1, d2 = e2 - x2, d3 = e3 - x3;
        lsum = d0 * d0 + d1 * d1 + d2 * d2 + d3 * d3;   // exact loss from true values
        ((float4*)out)[row * NGRP + tid] =
            make_float4(e0 * scale_q, e1 * scale_q, e2 * scale_q, e3 * scale_q);
    }
    #pragma unroll
    for (int off = 32; off > 0; off >>= 1) lsum += __shfl_down(lsum, off, 64);
    __syncthreads();
    if ((tid & 63) == 0 && tid < NGRP) s_red[tid >> 6] = lsum;
    __syncthreads();
    if (tid == 0) partial[row] = s_red[0] + s_red[1];
}

__global__ __launch_bounds__(256) void vq_finish(const float* __restrict__ partial,
                                                 float* __restrict__ out_loss)
{
    __shared__ float r[4];
    float v = partial[threadIdx.x] + partial[threadIdx.x + 256];
    #pragma unroll
    for (int off = 32; off > 0; off >>= 1) v += __shfl_down(v, off, 64);
    if ((threadIdx.x & 63) == 0) r[threadIdx.x >> 6] = v;
    __syncthreads();
    if (threadIdx.x == 0) {
        float t = (r[0] + r[1] + r[2] + r[3]) / 262144.f;
        out_loss[0] = t;
        out_loss[1] = t;
    }
}

extern "C" void kernel_launch(void* const* d_in, const int* in_sizes, int n_in,
                              void* d_out, int out_size, void* d_ws, size_t ws_size,
                              hipStream_t stream) {
    const float* feedback = (const float*)d_in[0];
    const float* embed    = (const float*)d_in[1];
    float* out     = (float*)d_out;
    float* partial = (float*)d_ws;

    vq_main<<<ROWS, NT, 0, stream>>>(feedback, embed, out, partial);
    vq_finish<<<1, 256, 0, stream>>>(partial, out + ROWS * DIMS);
}